// Round 2
// baseline (4444.339 us; speedup 1.0000x reference)
//
#include <hip/hip_runtime.h>
#include <hip/hip_bf16.h>

#define N_NODES 50000
#define DIM 128
#define E_EDGES 800000
#define L_LAYERS 3

typedef __attribute__((ext_vector_type(8))) short short8;
typedef __attribute__((ext_vector_type(4))) float f32x4;

__device__ __forceinline__ float bf_to_f(unsigned short u) {
    unsigned int x = ((unsigned int)u) << 16;
    return __builtin_bit_cast(float, x);
}
__device__ __forceinline__ unsigned short f_to_bf(float f) {
    unsigned int x = __builtin_bit_cast(unsigned int, f);
    unsigned int lsb = (x >> 16) & 1u;
    x += 0x7fffu + lsb;   // round-to-nearest-even
    return (unsigned short)(x >> 16);
}
__device__ __forceinline__ void split_bf(float f, unsigned short& hi, unsigned short& lo) {
    hi = f_to_bf(f);
    lo = f_to_bf(f - bf_to_f(hi));
}

// ---- float4 copy: h = x ----
__global__ __launch_bounds__(256) void copy4_kernel(const float4* __restrict__ in,
                                                    float4* __restrict__ out) {
    int i = blockIdx.x * 256 + threadIdx.x;
    out[i] = in[i];
}

// ---- z = (1+eps)*h ----
__global__ __launch_bounds__(256) void init_z_kernel(const float4* __restrict__ h,
                                                     const float* __restrict__ epsp,
                                                     float4* __restrict__ z) {
    int i = blockIdx.x * 256 + threadIdx.x;
    float s = 1.0f + epsp[0];
    float4 v = h[i];
    z[i] = make_float4(s * v.x, s * v.y, s * v.z, s * v.w);
}

// ---- W [L][K][Nn] fp32 -> Wt_hi/Wt_lo [L][Nn][K] bf16 (split) ----
__global__ __launch_bounds__(256) void trans_split_kernel(const float* __restrict__ w,
                                                          unsigned short* __restrict__ wt_hi,
                                                          unsigned short* __restrict__ wt_lo,
                                                          int K, int Nn) {
    int idx = blockIdx.x * 256 + threadIdx.x;
    int per = K * Nn;
    int l = idx / per;
    int r = idx - l * per;
    int k = r / Nn;
    int n = r - k * Nn;
    unsigned short hi, lo;
    split_bf(w[idx], hi, lo);
    size_t o = (size_t)l * per + (size_t)n * K + k;
    wt_hi[o] = hi;
    wt_lo[o] = lo;
}

// ---- edge scatter: z[dst] += h[src]  (fp32 atomics, 32 lanes/edge) ----
__global__ __launch_bounds__(256) void scatter_add_kernel(
        const float* __restrict__ h, const int* __restrict__ ei, float* __restrict__ z) {
    int gid = blockIdx.x * 256 + threadIdx.x;       // E*32 threads total
    int e = gid >> 5;
    int c = (gid & 31) << 2;                        // 4 floats per thread
    int src = ei[e];
    int dst = ei[E_EDGES + e];
    const float4 v = *(const float4*)(h + (size_t)src * DIM + c);
    float* a = z + (size_t)dst * DIM + c;
    atomicAdd(a + 0, v.x);
    atomicAdd(a + 1, v.y);
    atomicAdd(a + 2, v.z);
    atomicAdd(a + 3, v.w);
}

// ---- GEMM1: t = relu(bn( z @ W1 + b1 )) ; t split bf16 [N][256] ; K=128
// grid (ceil(N/64), 4) ; block 256
__global__ __launch_bounds__(256) void gemm1_kernel(
        const float* __restrict__ z,
        const unsigned short* __restrict__ w1t_hi,
        const unsigned short* __restrict__ w1t_lo,
        const float* __restrict__ b1, const float* __restrict__ g1,
        const float* __restrict__ be1, const float* __restrict__ m1,
        const float* __restrict__ v1,
        unsigned short* __restrict__ t_hi, unsigned short* __restrict__ t_lo) {
    const int K = 128;
    const int NN = 256;
    __shared__ unsigned short Ah[64][K + 8];
    __shared__ unsigned short Al[64][K + 8];
    __shared__ unsigned short Bh[64][K + 8];
    __shared__ unsigned short Bl[64][K + 8];
    const int tid = threadIdx.x;
    const int m0 = blockIdx.x * 64;
    const int n0 = blockIdx.y * 64;

    // stage A: split fp32 z -> hi/lo bf16
    for (int p = 0; p < 8; ++p) {
        int idx = p * 256 + tid;          // 64 rows x 32 float4-granules
        int r = idx >> 5;
        int c4 = (idx & 31) << 2;
        int rg = m0 + r;
        float4 v = make_float4(0.f, 0.f, 0.f, 0.f);
        if (rg < N_NODES) v = *(const float4*)(z + (size_t)rg * K + c4);
        unsigned short ph[4], pl[4];
        split_bf(v.x, ph[0], pl[0]);
        split_bf(v.y, ph[1], pl[1]);
        split_bf(v.z, ph[2], pl[2]);
        split_bf(v.w, ph[3], pl[3]);
        *(ushort4*)&Ah[r][c4] = *(ushort4*)ph;
        *(ushort4*)&Al[r][c4] = *(ushort4*)pl;
    }
    // stage B (pre-transposed, pre-split)
    for (int p = 0; p < 4; ++p) {
        int idx = p * 256 + tid;          // 64 rows x 16 granules of 8
        int r = idx >> 4;
        int g = idx & 15;
        size_t o = (size_t)(n0 + r) * K + g * 8;
        *(short8*)&Bh[r][g * 8] = *(const short8*)(w1t_hi + o);
        *(short8*)&Bl[r][g * 8] = *(const short8*)(w1t_lo + o);
    }
    __syncthreads();

    const int wave = tid >> 6;
    const int lane = tid & 63;
    const int quad = lane >> 4;
    const int l16 = lane & 15;
    f32x4 acc[4] = {};

    const int arow = wave * 16 + l16;
    for (int ks = 0; ks < 4; ++ks) {
        short8 ah = *(const short8*)&Ah[arow][ks * 32 + quad * 8];
        short8 al = *(const short8*)&Al[arow][ks * 32 + quad * 8];
        for (int nt = 0; nt < 4; ++nt) {
            short8 bh = *(const short8*)&Bh[nt * 16 + l16][ks * 32 + quad * 8];
            short8 bl = *(const short8*)&Bl[nt * 16 + l16][ks * 32 + quad * 8];
            acc[nt] = __builtin_amdgcn_mfma_f32_16x16x32_bf16(ah, bh, acc[nt], 0, 0, 0);
            acc[nt] = __builtin_amdgcn_mfma_f32_16x16x32_bf16(ah, bl, acc[nt], 0, 0, 0);
            acc[nt] = __builtin_amdgcn_mfma_f32_16x16x32_bf16(al, bh, acc[nt], 0, 0, 0);
        }
    }

    for (int nt = 0; nt < 4; ++nt) {
        int cg = n0 + nt * 16 + l16;
        float bias = b1[cg];
        float scale = g1[cg] * rsqrtf(v1[cg] + 1e-5f);
        float mean = m1[cg];
        float beta = be1[cg];
        for (int r = 0; r < 4; ++r) {
            int rg = m0 + wave * 16 + quad * 4 + r;
            if (rg < N_NODES) {
                float val = (acc[nt][r] + bias - mean) * scale + beta;
                val = fmaxf(val, 0.0f);
                unsigned short hi, lo;
                split_bf(val, hi, lo);
                t_hi[(size_t)rg * NN + cg] = hi;
                t_lo[(size_t)rg * NN + cg] = lo;
            }
        }
    }
}

// ---- GEMM2: h = (t @ W2 + b2) [+ bn+relu] ; h fp32 [N][128] ; K=256
// grid (ceil(N/64), 2) ; block 256
__global__ __launch_bounds__(256) void gemm2_kernel(
        const unsigned short* __restrict__ t_hi, const unsigned short* __restrict__ t_lo,
        const unsigned short* __restrict__ w2t_hi, const unsigned short* __restrict__ w2t_lo,
        const float* __restrict__ b2,
        const float* __restrict__ go, const float* __restrict__ bo,
        const float* __restrict__ mo, const float* __restrict__ vo,
        int do_bn,
        float* __restrict__ hout) {
    const int K = 256;
    const int BK = 128;
    __shared__ unsigned short Ah[64][BK + 8];
    __shared__ unsigned short Al[64][BK + 8];
    __shared__ unsigned short Bh[64][BK + 8];
    __shared__ unsigned short Bl[64][BK + 8];
    const int tid = threadIdx.x;
    const int m0 = blockIdx.x * 64;
    const int n0 = blockIdx.y * 64;

    const int wave = tid >> 6;
    const int lane = tid & 63;
    const int quad = lane >> 4;
    const int l16 = lane & 15;
    f32x4 acc[4] = {};

    for (int ko = 0; ko < 2; ++ko) {
        for (int p = 0; p < 4; ++p) {
            int idx = p * 256 + tid;
            int r = idx >> 4;
            int g = idx & 15;
            int rg = m0 + r;
            short8 vh = {}, vl = {};
            if (rg < N_NODES) {
                size_t o = (size_t)rg * K + ko * BK + g * 8;
                vh = *(const short8*)(t_hi + o);
                vl = *(const short8*)(t_lo + o);
            }
            *(short8*)&Ah[r][g * 8] = vh;
            *(short8*)&Al[r][g * 8] = vl;
        }
        for (int p = 0; p < 4; ++p) {
            int idx = p * 256 + tid;
            int r = idx >> 4;
            int g = idx & 15;
            size_t o = (size_t)(n0 + r) * K + ko * BK + g * 8;
            *(short8*)&Bh[r][g * 8] = *(const short8*)(w2t_hi + o);
            *(short8*)&Bl[r][g * 8] = *(const short8*)(w2t_lo + o);
        }
        __syncthreads();

        const int arow = wave * 16 + l16;
        for (int ks = 0; ks < 4; ++ks) {
            short8 ah = *(const short8*)&Ah[arow][ks * 32 + quad * 8];
            short8 al = *(const short8*)&Al[arow][ks * 32 + quad * 8];
            for (int nt = 0; nt < 4; ++nt) {
                short8 bh = *(const short8*)&Bh[nt * 16 + l16][ks * 32 + quad * 8];
                short8 bl = *(const short8*)&Bl[nt * 16 + l16][ks * 32 + quad * 8];
                acc[nt] = __builtin_amdgcn_mfma_f32_16x16x32_bf16(ah, bh, acc[nt], 0, 0, 0);
                acc[nt] = __builtin_amdgcn_mfma_f32_16x16x32_bf16(ah, bl, acc[nt], 0, 0, 0);
                acc[nt] = __builtin_amdgcn_mfma_f32_16x16x32_bf16(al, bh, acc[nt], 0, 0, 0);
            }
        }
        __syncthreads();
    }

    for (int nt = 0; nt < 4; ++nt) {
        int cg = n0 + nt * 16 + l16;
        float bias = b2[cg];
        float scale = 1.0f, mean = 0.0f, beta = 0.0f;
        if (do_bn) {
            scale = go[cg] * rsqrtf(vo[cg] + 1e-5f);
            mean = mo[cg];
            beta = bo[cg];
        }
        for (int r = 0; r < 4; ++r) {
            int rg = m0 + wave * 16 + quad * 4 + r;
            if (rg < N_NODES) {
                float val = acc[nt][r] + bias;
                if (do_bn) {
                    val = (val - mean) * scale + beta;
                    val = fmaxf(val, 0.0f);
                }
                hout[(size_t)rg * 128 + cg] = val;
            }
        }
    }
}

// ---- log_softmax over 128 cols, one wave per row, fp32 out ----
__global__ __launch_bounds__(256) void logsoftmax_kernel(
        const float* __restrict__ h, float* __restrict__ out) {
    int wave = threadIdx.x >> 6;
    int lane = threadIdx.x & 63;
    int row = blockIdx.x * 4 + wave;
    const float* hr = h + (size_t)row * DIM;
    float a = hr[lane];
    float b = hr[lane + 64];
    float m = fmaxf(a, b);
    for (int off = 32; off > 0; off >>= 1) m = fmaxf(m, __shfl_xor(m, off, 64));
    float s = expf(a - m) + expf(b - m);
    for (int off = 32; off > 0; off >>= 1) s += __shfl_xor(s, off, 64);
    float ls = logf(s);
    out[(size_t)row * DIM + lane] = a - m - ls;
    out[(size_t)row * DIM + lane + 64] = b - m - ls;
}

extern "C" void kernel_launch(void* const* d_in, const int* in_sizes, int n_in,
                              void* d_out, int out_size, void* d_ws, size_t ws_size,
                              hipStream_t stream) {
    const float* x   = (const float*)d_in[0];
    const int*   ei  = (const int*)d_in[1];
    const float* W1  = (const float*)d_in[2];
    const float* b1  = (const float*)d_in[3];
    const float* g1  = (const float*)d_in[4];
    const float* be1 = (const float*)d_in[5];
    const float* m1  = (const float*)d_in[6];
    const float* v1  = (const float*)d_in[7];
    const float* W2  = (const float*)d_in[8];
    const float* b2  = (const float*)d_in[9];
    const float* eps = (const float*)d_in[10];
    const float* go  = (const float*)d_in[11];
    const float* bo  = (const float*)d_in[12];
    const float* mo  = (const float*)d_in[13];
    const float* vo  = (const float*)d_in[14];

    char* ws = (char*)d_ws;
    float* h = (float*)ws;                   ws += (size_t)N_NODES * DIM * 4;       // 25.6 MB
    float* z = (float*)ws;                   ws += (size_t)N_NODES * DIM * 4;       // 25.6 MB
    unsigned short* t_hi = (unsigned short*)ws; ws += (size_t)N_NODES * 2 * DIM * 2; // 25.6 MB
    unsigned short* t_lo = (unsigned short*)ws; ws += (size_t)N_NODES * 2 * DIM * 2; // 25.6 MB
    unsigned short* w1t_hi = (unsigned short*)ws; ws += (size_t)L_LAYERS * DIM * 2 * DIM * 2;
    unsigned short* w1t_lo = (unsigned short*)ws; ws += (size_t)L_LAYERS * DIM * 2 * DIM * 2;
    unsigned short* w2t_hi = (unsigned short*)ws; ws += (size_t)L_LAYERS * DIM * 2 * DIM * 2;
    unsigned short* w2t_lo = (unsigned short*)ws; ws += (size_t)L_LAYERS * DIM * 2 * DIM * 2;

    copy4_kernel<<<(N_NODES * DIM / 4) / 256, 256, 0, stream>>>((const float4*)x, (float4*)h);
    trans_split_kernel<<<(L_LAYERS * DIM * 2 * DIM) / 256, 256, 0, stream>>>(W1, w1t_hi, w1t_lo, DIM, 2 * DIM);
    trans_split_kernel<<<(L_LAYERS * DIM * 2 * DIM) / 256, 256, 0, stream>>>(W2, w2t_hi, w2t_lo, 2 * DIM, DIM);

    const int mblocks = (N_NODES + 63) / 64;   // 782
    for (int i = 0; i < L_LAYERS; ++i) {
        init_z_kernel<<<(N_NODES * DIM / 4) / 256, 256, 0, stream>>>((const float4*)h, eps + i, (float4*)z);
        scatter_add_kernel<<<(E_EDGES * 32) / 256, 256, 0, stream>>>(h, ei, z);
        dim3 grid1(mblocks, 4);
        gemm1_kernel<<<grid1, 256, 0, stream>>>(z,
            w1t_hi + (size_t)i * 256 * 128, w1t_lo + (size_t)i * 256 * 128,
            b1 + i * 256, g1 + i * 256, be1 + i * 256, m1 + i * 256, v1 + i * 256,
            t_hi, t_lo);
        dim3 grid2(mblocks, 2);
        int do_bn = (i < L_LAYERS - 1) ? 1 : 0;
        int oi = do_bn ? i : 0;
        gemm2_kernel<<<grid2, 256, 0, stream>>>(t_hi, t_lo,
            w2t_hi + (size_t)i * 128 * 256, w2t_lo + (size_t)i * 128 * 256,
            b2 + i * 128,
            go + oi * 128, bo + oi * 128, mo + oi * 128, vo + oi * 128,
            do_bn, h);
    }
    logsoftmax_kernel<<<N_NODES / 4, 256, 0, stream>>>(h, (float*)d_out);
}

// Round 3
// 681.194 us; speedup vs baseline: 6.5243x; 6.5243x over previous
//
#include <hip/hip_runtime.h>
#include <hip/hip_bf16.h>

#define N_NODES 50000
#define DIM 128
#define E_EDGES 800000
#define L_LAYERS 3
#define SCAN_BLOCKS 196   // ceil(50000/256)

typedef __attribute__((ext_vector_type(8))) short short8;
typedef __attribute__((ext_vector_type(4))) float f32x4;

__device__ __forceinline__ float bf_to_f(unsigned short u) {
    unsigned int x = ((unsigned int)u) << 16;
    return __builtin_bit_cast(float, x);
}
__device__ __forceinline__ unsigned short f_to_bf(float f) {
    unsigned int x = __builtin_bit_cast(unsigned int, f);
    unsigned int lsb = (x >> 16) & 1u;
    x += 0x7fffu + lsb;   // round-to-nearest-even
    return (unsigned short)(x >> 16);
}
__device__ __forceinline__ void split_bf(float f, unsigned short& hi, unsigned short& lo) {
    hi = f_to_bf(f);
    lo = f_to_bf(f - bf_to_f(hi));
}

// ---- float4 copy: h = x ----
__global__ __launch_bounds__(256) void copy4_kernel(const float4* __restrict__ in,
                                                    float4* __restrict__ out) {
    int i = blockIdx.x * 256 + threadIdx.x;
    out[i] = in[i];
}

// ---- W [L][K][Nn] fp32 -> Wt_hi/Wt_lo [L][Nn][K] bf16 (split) ----
__global__ __launch_bounds__(256) void trans_split_kernel(const float* __restrict__ w,
                                                          unsigned short* __restrict__ wt_hi,
                                                          unsigned short* __restrict__ wt_lo,
                                                          int K, int Nn) {
    int idx = blockIdx.x * 256 + threadIdx.x;
    int per = K * Nn;
    int l = idx / per;
    int r = idx - l * per;
    int k = r / Nn;
    int n = r - k * Nn;
    unsigned short hi, lo;
    split_bf(w[idx], hi, lo);
    size_t o = (size_t)l * per + (size_t)n * K + k;
    wt_hi[o] = hi;
    wt_lo[o] = lo;
}

// ================= CSR build (once per call; graph shared by all layers) ====

__global__ __launch_bounds__(256) void histogram_kernel(const int* __restrict__ ei,
                                                        int* __restrict__ deg) {
    int e = blockIdx.x * 256 + threadIdx.x;          // E threads
    atomicAdd(&deg[ei[E_EDGES + e]], 1);
}

// block-level inclusive scan -> exclusive-in-block prefix + block sums
__global__ __launch_bounds__(256) void scan1_kernel(const int* __restrict__ deg,
                                                    int* __restrict__ rowtmp,
                                                    int* __restrict__ bsum) {
    __shared__ int s[256];
    int t = threadIdx.x;
    int idx = blockIdx.x * 256 + t;
    int v = (idx < N_NODES) ? deg[idx] : 0;
    s[t] = v;
    __syncthreads();
    for (int off = 1; off < 256; off <<= 1) {
        int x = s[t];
        int y = (t >= off) ? s[t - off] : 0;
        __syncthreads();
        s[t] = x + y;
        __syncthreads();
    }
    if (idx < N_NODES) rowtmp[idx] = s[t] - v;
    if (t == 255) bsum[blockIdx.x] = s[255];
}

__global__ __launch_bounds__(256) void scan2_kernel(int* __restrict__ bsum) {
    __shared__ int s[256];
    int t = threadIdx.x;
    int v = (t < SCAN_BLOCKS) ? bsum[t] : 0;
    s[t] = v;
    __syncthreads();
    for (int off = 1; off < 256; off <<= 1) {
        int x = s[t];
        int y = (t >= off) ? s[t - off] : 0;
        __syncthreads();
        s[t] = x + y;
        __syncthreads();
    }
    if (t < SCAN_BLOCKS) bsum[t] = s[t] - v;   // exclusive
}

__global__ __launch_bounds__(256) void scan3_kernel(const int* __restrict__ rowtmp,
                                                    const int* __restrict__ bsum,
                                                    int* __restrict__ row,
                                                    int* __restrict__ cursor) {
    int idx = blockIdx.x * 256 + threadIdx.x;
    if (idx < N_NODES) {
        int rs = rowtmp[idx] + bsum[blockIdx.x];
        row[idx] = rs;
        cursor[idx] = rs;
    }
    if (idx == 0) row[N_NODES] = E_EDGES;
}

__global__ __launch_bounds__(256) void fill_kernel(const int* __restrict__ ei,
                                                   int* __restrict__ cursor,
                                                   int* __restrict__ col) {
    int e = blockIdx.x * 256 + threadIdx.x;          // E threads
    int dst = ei[E_EDGES + e];
    int pos = atomicAdd(&cursor[dst], 1);
    col[pos] = ei[e];
}

// ---- aggregation (gather): z[i] = (1+eps)*h[i] + sum_{j in N(i)} h[j] ----
// one wave per node; lane owns a float2 (128 cols / 64 lanes)
__global__ __launch_bounds__(256) void aggregate_kernel(
        const float* __restrict__ h, const int* __restrict__ row,
        const int* __restrict__ col, const float* __restrict__ epsp,
        float* __restrict__ z) {
    int wv = threadIdx.x >> 6;
    int lane = threadIdx.x & 63;
    int node = blockIdx.x * 4 + wv;                  // grid = 12500 exactly
    const float2* hp = (const float2*)h;
    size_t base = ((size_t)node * DIM) >> 1;
    float s = 1.0f + epsp[0];
    float2 hv = hp[base + lane];
    float ax = s * hv.x, ay = s * hv.y;
    int e = row[node], e1 = row[node + 1];
    for (; e + 1 < e1; e += 2) {
        int s0 = col[e];
        int s1 = col[e + 1];
        float2 v0 = hp[(((size_t)s0 * DIM) >> 1) + lane];
        float2 v1 = hp[(((size_t)s1 * DIM) >> 1) + lane];
        ax += v0.x + v1.x;
        ay += v0.y + v1.y;
    }
    if (e < e1) {
        float2 v = hp[(((size_t)col[e] * DIM) >> 1) + lane];
        ax += v.x;
        ay += v.y;
    }
    ((float2*)z)[base + lane] = make_float2(ax, ay);
}

// ---- GEMM1: t = relu(bn( z @ W1 + b1 )) ; t split bf16 [N][256] ; K=128
__global__ __launch_bounds__(256) void gemm1_kernel(
        const float* __restrict__ z,
        const unsigned short* __restrict__ w1t_hi,
        const unsigned short* __restrict__ w1t_lo,
        const float* __restrict__ b1, const float* __restrict__ g1,
        const float* __restrict__ be1, const float* __restrict__ m1,
        const float* __restrict__ v1,
        unsigned short* __restrict__ t_hi, unsigned short* __restrict__ t_lo) {
    const int K = 128;
    const int NN = 256;
    __shared__ unsigned short Ah[64][K + 8];
    __shared__ unsigned short Al[64][K + 8];
    __shared__ unsigned short Bh[64][K + 8];
    __shared__ unsigned short Bl[64][K + 8];
    const int tid = threadIdx.x;
    const int m0 = blockIdx.x * 64;
    const int n0 = blockIdx.y * 64;

    for (int p = 0; p < 8; ++p) {
        int idx = p * 256 + tid;
        int r = idx >> 5;
        int c4 = (idx & 31) << 2;
        int rg = m0 + r;
        float4 v = make_float4(0.f, 0.f, 0.f, 0.f);
        if (rg < N_NODES) v = *(const float4*)(z + (size_t)rg * K + c4);
        unsigned short ph[4], pl[4];
        split_bf(v.x, ph[0], pl[0]);
        split_bf(v.y, ph[1], pl[1]);
        split_bf(v.z, ph[2], pl[2]);
        split_bf(v.w, ph[3], pl[3]);
        *(ushort4*)&Ah[r][c4] = *(ushort4*)ph;
        *(ushort4*)&Al[r][c4] = *(ushort4*)pl;
    }
    for (int p = 0; p < 4; ++p) {
        int idx = p * 256 + tid;
        int r = idx >> 4;
        int g = idx & 15;
        size_t o = (size_t)(n0 + r) * K + g * 8;
        *(short8*)&Bh[r][g * 8] = *(const short8*)(w1t_hi + o);
        *(short8*)&Bl[r][g * 8] = *(const short8*)(w1t_lo + o);
    }
    __syncthreads();

    const int wave = tid >> 6;
    const int lane = tid & 63;
    const int quad = lane >> 4;
    const int l16 = lane & 15;
    f32x4 acc[4] = {};

    const int arow = wave * 16 + l16;
    for (int ks = 0; ks < 4; ++ks) {
        short8 ah = *(const short8*)&Ah[arow][ks * 32 + quad * 8];
        short8 al = *(const short8*)&Al[arow][ks * 32 + quad * 8];
        for (int nt = 0; nt < 4; ++nt) {
            short8 bh = *(const short8*)&Bh[nt * 16 + l16][ks * 32 + quad * 8];
            short8 bl = *(const short8*)&Bl[nt * 16 + l16][ks * 32 + quad * 8];
            acc[nt] = __builtin_amdgcn_mfma_f32_16x16x32_bf16(ah, bh, acc[nt], 0, 0, 0);
            acc[nt] = __builtin_amdgcn_mfma_f32_16x16x32_bf16(ah, bl, acc[nt], 0, 0, 0);
            acc[nt] = __builtin_amdgcn_mfma_f32_16x16x32_bf16(al, bh, acc[nt], 0, 0, 0);
        }
    }

    for (int nt = 0; nt < 4; ++nt) {
        int cg = n0 + nt * 16 + l16;
        float bias = b1[cg];
        float scale = g1[cg] * rsqrtf(v1[cg] + 1e-5f);
        float mean = m1[cg];
        float beta = be1[cg];
        for (int r = 0; r < 4; ++r) {
            int rg = m0 + wave * 16 + quad * 4 + r;
            if (rg < N_NODES) {
                float val = (acc[nt][r] + bias - mean) * scale + beta;
                val = fmaxf(val, 0.0f);
                unsigned short hi, lo;
                split_bf(val, hi, lo);
                t_hi[(size_t)rg * NN + cg] = hi;
                t_lo[(size_t)rg * NN + cg] = lo;
            }
        }
    }
}

// ---- GEMM2: h = (t @ W2 + b2) [+ bn+relu] ; h fp32 [N][128] ; K=256
__global__ __launch_bounds__(256) void gemm2_kernel(
        const unsigned short* __restrict__ t_hi, const unsigned short* __restrict__ t_lo,
        const unsigned short* __restrict__ w2t_hi, const unsigned short* __restrict__ w2t_lo,
        const float* __restrict__ b2,
        const float* __restrict__ go, const float* __restrict__ bo,
        const float* __restrict__ mo, const float* __restrict__ vo,
        int do_bn,
        float* __restrict__ hout) {
    const int K = 256;
    const int BK = 128;
    __shared__ unsigned short Ah[64][BK + 8];
    __shared__ unsigned short Al[64][BK + 8];
    __shared__ unsigned short Bh[64][BK + 8];
    __shared__ unsigned short Bl[64][BK + 8];
    const int tid = threadIdx.x;
    const int m0 = blockIdx.x * 64;
    const int n0 = blockIdx.y * 64;

    const int wave = tid >> 6;
    const int lane = tid & 63;
    const int quad = lane >> 4;
    const int l16 = lane & 15;
    f32x4 acc[4] = {};

    for (int ko = 0; ko < 2; ++ko) {
        for (int p = 0; p < 4; ++p) {
            int idx = p * 256 + tid;
            int r = idx >> 4;
            int g = idx & 15;
            int rg = m0 + r;
            short8 vh = {}, vl = {};
            if (rg < N_NODES) {
                size_t o = (size_t)rg * K + ko * BK + g * 8;
                vh = *(const short8*)(t_hi + o);
                vl = *(const short8*)(t_lo + o);
            }
            *(short8*)&Ah[r][g * 8] = vh;
            *(short8*)&Al[r][g * 8] = vl;
        }
        for (int p = 0; p < 4; ++p) {
            int idx = p * 256 + tid;
            int r = idx >> 4;
            int g = idx & 15;
            size_t o = (size_t)(n0 + r) * K + ko * BK + g * 8;
            *(short8*)&Bh[r][g * 8] = *(const short8*)(w2t_hi + o);
            *(short8*)&Bl[r][g * 8] = *(const short8*)(w2t_lo + o);
        }
        __syncthreads();

        const int arow = wave * 16 + l16;
        for (int ks = 0; ks < 4; ++ks) {
            short8 ah = *(const short8*)&Ah[arow][ks * 32 + quad * 8];
            short8 al = *(const short8*)&Al[arow][ks * 32 + quad * 8];
            for (int nt = 0; nt < 4; ++nt) {
                short8 bh = *(const short8*)&Bh[nt * 16 + l16][ks * 32 + quad * 8];
                short8 bl = *(const short8*)&Bl[nt * 16 + l16][ks * 32 + quad * 8];
                acc[nt] = __builtin_amdgcn_mfma_f32_16x16x32_bf16(ah, bh, acc[nt], 0, 0, 0);
                acc[nt] = __builtin_amdgcn_mfma_f32_16x16x32_bf16(ah, bl, acc[nt], 0, 0, 0);
                acc[nt] = __builtin_amdgcn_mfma_f32_16x16x32_bf16(al, bh, acc[nt], 0, 0, 0);
            }
        }
        __syncthreads();
    }

    for (int nt = 0; nt < 4; ++nt) {
        int cg = n0 + nt * 16 + l16;
        float bias = b2[cg];
        float scale = 1.0f, mean = 0.0f, beta = 0.0f;
        if (do_bn) {
            scale = go[cg] * rsqrtf(vo[cg] + 1e-5f);
            mean = mo[cg];
            beta = bo[cg];
        }
        for (int r = 0; r < 4; ++r) {
            int rg = m0 + wave * 16 + quad * 4 + r;
            if (rg < N_NODES) {
                float val = acc[nt][r] + bias;
                if (do_bn) {
                    val = (val - mean) * scale + beta;
                    val = fmaxf(val, 0.0f);
                }
                hout[(size_t)rg * 128 + cg] = val;
            }
        }
    }
}

// ---- log_softmax over 128 cols, one wave per row, fp32 out ----
__global__ __launch_bounds__(256) void logsoftmax_kernel(
        const float* __restrict__ h, float* __restrict__ out) {
    int wave = threadIdx.x >> 6;
    int lane = threadIdx.x & 63;
    int row = blockIdx.x * 4 + wave;
    const float* hr = h + (size_t)row * DIM;
    float a = hr[lane];
    float b = hr[lane + 64];
    float m = fmaxf(a, b);
    for (int off = 32; off > 0; off >>= 1) m = fmaxf(m, __shfl_xor(m, off, 64));
    float s = expf(a - m) + expf(b - m);
    for (int off = 32; off > 0; off >>= 1) s += __shfl_xor(s, off, 64);
    float ls = logf(s);
    out[(size_t)row * DIM + lane] = a - m - ls;
    out[(size_t)row * DIM + lane + 64] = b - m - ls;
}

extern "C" void kernel_launch(void* const* d_in, const int* in_sizes, int n_in,
                              void* d_out, int out_size, void* d_ws, size_t ws_size,
                              hipStream_t stream) {
    const float* x   = (const float*)d_in[0];
    const int*   ei  = (const int*)d_in[1];
    const float* W1  = (const float*)d_in[2];
    const float* b1  = (const float*)d_in[3];
    const float* g1  = (const float*)d_in[4];
    const float* be1 = (const float*)d_in[5];
    const float* m1  = (const float*)d_in[6];
    const float* v1  = (const float*)d_in[7];
    const float* W2  = (const float*)d_in[8];
    const float* b2  = (const float*)d_in[9];
    const float* eps = (const float*)d_in[10];
    const float* go  = (const float*)d_in[11];
    const float* bo  = (const float*)d_in[12];
    const float* mo  = (const float*)d_in[13];
    const float* vo  = (const float*)d_in[14];

    char* ws = (char*)d_ws;
    float* h = (float*)ws;                      ws += (size_t)N_NODES * DIM * 4;
    float* z = (float*)ws;                      ws += (size_t)N_NODES * DIM * 4;
    unsigned short* t_hi = (unsigned short*)ws; ws += (size_t)N_NODES * 2 * DIM * 2;
    unsigned short* t_lo = (unsigned short*)ws; ws += (size_t)N_NODES * 2 * DIM * 2;
    unsigned short* w1t_hi = (unsigned short*)ws; ws += (size_t)L_LAYERS * DIM * 2 * DIM * 2;
    unsigned short* w1t_lo = (unsigned short*)ws; ws += (size_t)L_LAYERS * DIM * 2 * DIM * 2;
    unsigned short* w2t_hi = (unsigned short*)ws; ws += (size_t)L_LAYERS * DIM * 2 * DIM * 2;
    unsigned short* w2t_lo = (unsigned short*)ws; ws += (size_t)L_LAYERS * DIM * 2 * DIM * 2;
    int* deg    = (int*)ws; ws += (size_t)N_NODES * 4;
    int* rowtmp = (int*)ws; ws += (size_t)N_NODES * 4;
    int* rowp   = (int*)ws; ws += (size_t)(N_NODES + 1) * 4;
    int* cursor = (int*)ws; ws += (size_t)N_NODES * 4;
    int* bsum   = (int*)ws; ws += 256 * 4;
    int* col    = (int*)ws; ws += (size_t)E_EDGES * 4;

    // ---- CSR build (graph is layer-invariant) ----
    hipMemsetAsync(deg, 0, (size_t)N_NODES * 4, stream);
    histogram_kernel<<<E_EDGES / 256, 256, 0, stream>>>(ei, deg);
    scan1_kernel<<<SCAN_BLOCKS, 256, 0, stream>>>(deg, rowtmp, bsum);
    scan2_kernel<<<1, 256, 0, stream>>>(bsum);
    scan3_kernel<<<SCAN_BLOCKS, 256, 0, stream>>>(rowtmp, bsum, rowp, cursor);
    fill_kernel<<<E_EDGES / 256, 256, 0, stream>>>(ei, cursor, col);

    copy4_kernel<<<(N_NODES * DIM / 4) / 256, 256, 0, stream>>>((const float4*)x, (float4*)h);
    trans_split_kernel<<<(L_LAYERS * DIM * 2 * DIM) / 256, 256, 0, stream>>>(W1, w1t_hi, w1t_lo, DIM, 2 * DIM);
    trans_split_kernel<<<(L_LAYERS * DIM * 2 * DIM) / 256, 256, 0, stream>>>(W2, w2t_hi, w2t_lo, 2 * DIM, DIM);

    const int mblocks = (N_NODES + 63) / 64;   // 782
    for (int i = 0; i < L_LAYERS; ++i) {
        aggregate_kernel<<<N_NODES / 4, 256, 0, stream>>>(h, rowp, col, eps + i, z);
        dim3 grid1(mblocks, 4);
        gemm1_kernel<<<grid1, 256, 0, stream>>>(z,
            w1t_hi + (size_t)i * 256 * 128, w1t_lo + (size_t)i * 256 * 128,
            b1 + i * 256, g1 + i * 256, be1 + i * 256, m1 + i * 256, v1 + i * 256,
            t_hi, t_lo);
        dim3 grid2(mblocks, 2);
        int do_bn = (i < L_LAYERS - 1) ? 1 : 0;
        int oi = do_bn ? i : 0;
        gemm2_kernel<<<grid2, 256, 0, stream>>>(t_hi, t_lo,
            w2t_hi + (size_t)i * 128 * 256, w2t_lo + (size_t)i * 128 * 256,
            b2 + i * 128,
            go + oi * 128, bo + oi * 128, mo + oi * 128, vo + oi * 128,
            do_bn, h);
    }
    logsoftmax_kernel<<<N_NODES / 4, 256, 0, stream>>>(h, (float*)d_out);
}